// Round 7
// baseline (218.007 us; speedup 1.0000x reference)
//
#include <hip/hip_runtime.h>
#include <stdint.h>

typedef unsigned short u16;
typedef unsigned int u32;
typedef __attribute__((ext_vector_type(8))) short bf16x8;
typedef __attribute__((ext_vector_type(4))) float f32x4;

#define NTOK 1024      // H*W
#define DMODEL 256
#define NHEAD 8
#define DK 32
#define NBATCH 8
#define PER_B (DMODEL * NTOK)   // 262144

// attn LDS layout (u16 units)
#define KS_STRIDE 34            // 17 dwords (odd) per key row
#define VT_STRIDE 1034          // 517 dwords (odd) per dv row
#define PS_STRIDE 134           // 67 dwords (odd) per q row
#define KS_OFF 0                               // 1024*34   = 34816 u16
#define VT_OFF 34816                           // 32*1034   = 33088 u16
#define PS_OFF (34816 + 33088)                 // 4*16*134  = 8576  u16
#define ATTN_LDS_BYTES ((PS_OFF + 4 * 16 * PS_STRIDE) * 2)   // 152960 B

__device__ __forceinline__ float b2f(u16 h) {
    union { unsigned u; float f; } c; c.u = ((unsigned)h) << 16; return c.f;
}
__device__ __forceinline__ u16 f2b(float f) {
    unsigned u = __float_as_uint(f);
    unsigned r = u + 0x7fffu + ((u >> 16) & 1u);
    return (u16)(r >> 16);
}

// ---------------- Kernel 1: fused weight-convert + LN partial sums ----------------
__global__ void prep(const float* __restrict__ Wq, const float* __restrict__ Wk,
                     const float* __restrict__ Wv, const float* __restrict__ Wo,
                     u16* __restrict__ wb,
                     const float* __restrict__ x, float* __restrict__ part) {
    int bx = blockIdx.x;
    int t = threadIdx.x;
    if (bx < 256) {
        int m = bx >> 6;
        const float* W = (m == 0) ? Wq : (m == 1) ? Wk : (m == 2) ? Wv : Wo;
        int i = ((bx & 63) * 256 + t) * 4;
        float4 v = *(const float4*)&W[i];
        ushort4 o;
        o.x = f2b(v.x); o.y = f2b(v.y); o.z = f2b(v.z); o.w = f2b(v.w);
        *(ushort4*)&wb[m * 65536 + i] = o;
        return;
    }
    int blk = bx - 256;
    int b = blk >> 3, sl = blk & 7;
    int w = t >> 6, l = t & 63;
    const float* xb = x + (size_t)b * PER_B + sl * (PER_B / 8);
    float s = 0.f, ss = 0.f;
    for (int base = 0; base < PER_B / 8; base += 1024) {
        float4 v = *(const float4*)&xb[base + t * 4];
        s += v.x + v.y + v.z + v.w;
        ss += v.x * v.x + v.y * v.y + v.z * v.z + v.w * v.w;
    }
    for (int d = 1; d < 64; d <<= 1) {
        s += __shfl_xor(s, d, 64);
        ss += __shfl_xor(ss, d, 64);
    }
    __shared__ float red[2][4];
    if (l == 0) { red[0][w] = s; red[1][w] = ss; }
    __syncthreads();
    if (t == 0) {
        float S = red[0][0] + red[0][1] + red[0][2] + red[0][3];
        float SS = red[1][0] + red[1][1] + red[1][2] + red[1][3];
        part[(b * 8 + sl) * 2] = S;
        part[(b * 8 + sl) * 2 + 1] = SS;
    }
}

// ---------------- Kernel 2: normalize + transpose [c,n] -> [n,c], fp32 -> bf16 ----------------
__global__ void normT(const float* __restrict__ x, const float* __restrict__ part,
                      u16* __restrict__ xn) {
    int b = blockIdx.z;
    int n0 = blockIdx.x * 32;
    int c0 = blockIdx.y * 32;
    int tx = threadIdx.x, ty = threadIdx.y;   // (32, 8)
    __shared__ float s_mu, s_rs;
    __shared__ float tile[32][33];
    if (tx == 0 && ty == 0) {
        float S = 0.f, SS = 0.f;
        for (int i = 0; i < 8; ++i) { S += part[(b * 8 + i) * 2]; SS += part[(b * 8 + i) * 2 + 1]; }
        float mu = S / (float)PER_B;
        float var = SS / (float)PER_B - mu * mu;
        s_mu = mu;
        s_rs = rsqrtf(var + 1e-5f);
    }
    __syncthreads();
    float mu = s_mu, rs = s_rs;
    const float* xb = x + (size_t)b * PER_B;
#pragma unroll
    for (int i = 0; i < 4; ++i) {
        int c = c0 + ty + i * 8;
        tile[ty + i * 8][tx] = (xb[c * NTOK + n0 + tx] - mu) * rs;
    }
    __syncthreads();
    u16* xnb = xn + (size_t)b * PER_B;
#pragma unroll
    for (int i = 0; i < 4; ++i) {
        int n = n0 + ty + i * 8;
        xnb[n * DMODEL + c0 + tx] = f2b(tile[tx][ty + i * 8]);
    }
}

// ---------------- Kernel 3: QKV projection GEMM (LDS-staged) ----------------
// q-scale folds DK^-0.5 * log2(e) for attn's exp2 path.
__global__ __launch_bounds__(256) void qkv_gemm(
    const u16* __restrict__ xn, const u16* __restrict__ wb,
    const float* __restrict__ bq, const float* __restrict__ bk,
    const float* __restrict__ bv,
    u16* __restrict__ qo, u16* __restrict__ ko, u16* __restrict__ vo) {
    int mt = blockIdx.x;
    int ot = blockIdx.y;
    int b = blockIdx.z;
    int sel = ot >> 2;            // 0=q 1=k 2=v
    int o0 = (ot & 3) * 64;
    const u16* W = wb + sel * 65536;
    const float* bias = (sel == 0) ? bq : (sel == 1) ? bk : bv;

    __shared__ u16 As[64][40];
    __shared__ u16 Bs[64][40];
    int t = threadIdx.x;
    int w = t >> 6, l = t & 63;
    int lr = t >> 2;
    int lc = (t & 3) * 8;
    int qd = l >> 4, ln = l & 15;

    const u16* xb = xn + ((size_t)b * NTOK + mt * 64) * DMODEL;
    f32x4 acc[4] = {};
    for (int kb = 0; kb < 8; ++kb) {
        *(uint4*)&As[lr][lc] = *(const uint4*)&xb[lr * DMODEL + kb * 32 + lc];
        *(uint4*)&Bs[lr][lc] = *(const uint4*)&W[(o0 + lr) * DMODEL + kb * 32 + lc];
        __syncthreads();
        bf16x8 af = *(const bf16x8*)&As[w * 16 + ln][qd * 8];
#pragma unroll
        for (int ns = 0; ns < 4; ++ns) {
            bf16x8 bf = *(const bf16x8*)&Bs[ns * 16 + ln][qd * 8];
            acc[ns] = __builtin_amdgcn_mfma_f32_16x16x32_bf16(af, bf, acc[ns], 0, 0, 0);
        }
        __syncthreads();
    }
    if (sel < 2) {
        u16* outp = (sel == 0) ? qo : ko;
        // q: DK^-0.5 * log2(e) so attn uses exp2 directly
        float scale = (sel == 0) ? 0.25505654344884634f : 1.0f;
#pragma unroll
        for (int ns = 0; ns < 4; ++ns) {
            int o = o0 + ns * 16 + ln;
            float bias_f = bias[o];
            int head = o >> 5, d = o & 31;
#pragma unroll
            for (int r = 0; r < 4; ++r) {
                int n_row = mt * 64 + w * 16 + qd * 4 + r;
                float v = (acc[ns][r] + bias_f) * scale;
                outp[(((size_t)b * NHEAD + head) * NTOK + n_row) * DK + d] = f2b(v);
            }
        }
    } else {
        // V transposed: vo[bh][dv][n]
        int n0 = mt * 64 + w * 16 + qd * 4;
#pragma unroll
        for (int ns = 0; ns < 4; ++ns) {
            int o = o0 + ns * 16 + ln;
            float bias_f = bias[o];
            int head = o >> 5, d = o & 31;
            ushort4 pk;
            pk.x = f2b(acc[ns][0] + bias_f);
            pk.y = f2b(acc[ns][1] + bias_f);
            pk.z = f2b(acc[ns][2] + bias_f);
            pk.w = f2b(acc[ns][3] + bias_f);
            *(ushort4*)&vo[(((size_t)b * NHEAD + head) * DK + d) * NTOK + n0] = pk;
        }
    }
}

// ---------------- Kernel 4: attention — K/V fully LDS-resident ----------------
// grid (64 bh, 4 qq) = 256 blocks = 1/CU, zero tail; bh fastest -> XCD L2 affinity.
// Stage all K [1024][32] and Vt [32][1024] into LDS ONCE (32 contiguous uint4/thread),
// one __syncthreads, then 4 waves each process 4 q-subtiles x 1024 keys with ZERO
// global reads and ZERO barriers in the hot loop. S^T = mfma(kf, qf) -> exp2 ->
// packed-b64 P (per-wave LDS tile) -> PV with 4 interleaved accumulators.
__global__ __launch_bounds__(256) void attn(
    const u16* __restrict__ qws, const u16* __restrict__ kws,
    const u16* __restrict__ vtws, u16* __restrict__ tmp) {
    extern __shared__ u16 lds[];
    int bh = blockIdx.x;
    int qq = blockIdx.y;
    int b = bh >> 3, h = bh & 7;
    const u16* Q  = qws  + (size_t)bh * NTOK * DK;
    const u16* K  = kws  + (size_t)bh * NTOK * DK;
    const u16* Vt = vtws + (size_t)bh * DK * NTOK;   // [dv][n]

    u16* Ksh = lds + KS_OFF;    // [1024][34]
    u16* Vsh = lds + VT_OFF;    // [32][1034]
    u16* Psh = lds + PS_OFF;    // [4][16][134]

    int t = threadIdx.x;
    int w = t >> 6, l = t & 63;
    int qd = l >> 4, ln = l & 15;

    // ---- stage K (64 KB) and Vt (64 KB): contiguous global, padded LDS rows ----
#pragma unroll
    for (int i = 0; i < 16; ++i) {
        int idx = i * 256 + t;                 // 0..4095 uint4s
        int row = idx >> 2, col = (idx & 3) * 8;
        *(uint4*)&Ksh[row * KS_STRIDE + col] = *(const uint4*)&K[idx * 8];
    }
#pragma unroll
    for (int i = 0; i < 16; ++i) {
        int idx = i * 256 + t;
        int row = idx >> 7, col = (idx & 127) * 8;
        *(uint4*)&Vsh[row * VT_STRIDE + col] = *(const uint4*)&Vt[idx * 8];
    }
    // prefetch all 4 Q fragments for this wave (independent, overlap staging)
    bf16x8 qf[4];
#pragma unroll
    for (int sub = 0; sub < 4; ++sub) {
        int q0 = qq * 256 + sub * 64 + w * 16;
        qf[sub] = *(const bf16x8*)&Q[(q0 + ln) * DK + qd * 8];
    }
    __syncthreads();   // the only barrier

    u16* psw = Psh + w * 16 * PS_STRIDE;
    int wadr[8];
#pragma unroll
    for (int ns = 0; ns < 8; ++ns)
        wadr[ns] = ln * PS_STRIDE + ns * 16 + qd * 4;   // b64: keys ns*16+qd*4..+3, q-row ln
    const bf16x8* rdp[4];
#pragma unroll
    for (int ks = 0; ks < 4; ++ks)
        rdp[ks] = (const bf16x8*)&psw[ln * PS_STRIDE + ks * 32 + qd * 8];

    for (int sub = 0; sub < 4; ++sub) {
        float lsum = 0.f;
        f32x4 oa[4] = {};   // [dvhalf*2 + chain]
        for (int c = 0; c < 8; ++c) {
            // S^T over 128 keys: 8 independent MFMAs; exp2; packed b64 P writes
#pragma unroll
            for (int ns = 0; ns < 8; ++ns) {
                bf16x8 kf = *(const bf16x8*)&Ksh[(c * 128 + ns * 16 + ln) * KS_STRIDE + qd * 8];
                f32x4 z = {0.f, 0.f, 0.f, 0.f};
                f32x4 s = __builtin_amdgcn_mfma_f32_16x16x32_bf16(kf, qf[sub], z, 0, 0, 0);
                float p0 = __builtin_amdgcn_exp2f(s[0]);
                float p1 = __builtin_amdgcn_exp2f(s[1]);
                float p2 = __builtin_amdgcn_exp2f(s[2]);
                float p3 = __builtin_amdgcn_exp2f(s[3]);
                lsum += (p0 + p1) + (p2 + p3);
                u32 dw0 = __builtin_amdgcn_perm(__float_as_uint(p1), __float_as_uint(p0), 0x07060302u);
                u32 dw1 = __builtin_amdgcn_perm(__float_as_uint(p3), __float_as_uint(p2), 0x07060302u);
                *(uint2*)&psw[wadr[ns]] = make_uint2(dw0, dw1);
            }
            // PV over the 128 keys; even/odd ks use separate accumulators (chain split)
#pragma unroll
            for (int ks = 0; ks < 4; ++ks) {
                bf16x8 pf = *rdp[ks];
                bf16x8 vf0 = *(const bf16x8*)&Vsh[( 0 + ln) * VT_STRIDE + c * 128 + ks * 32 + qd * 8];
                bf16x8 vf1 = *(const bf16x8*)&Vsh[(16 + ln) * VT_STRIDE + c * 128 + ks * 32 + qd * 8];
                int ch = ks & 1;
                oa[ch]     = __builtin_amdgcn_mfma_f32_16x16x32_bf16(pf, vf0, oa[ch], 0, 0, 0);
                oa[2 + ch] = __builtin_amdgcn_mfma_f32_16x16x32_bf16(pf, vf1, oa[2 + ch], 0, 0, 0);
            }
        }
        f32x4 o0 = oa[0] + oa[1];
        f32x4 o1 = oa[2] + oa[3];
        // l: keys split across qd -> reduce over qd
        lsum += __shfl_xor(lsum, 16, 64);
        lsum += __shfl_xor(lsum, 32, 64);
        float linv[4];
#pragma unroll
        for (int r = 0; r < 4; ++r)
            linv[r] = 1.0f / __shfl(lsum, qd * 4 + r, 64);
        // epilogue: tmp[b][n][h*32 + dv]
        int q0 = qq * 256 + sub * 64 + w * 16;
#pragma unroll
        for (int r = 0; r < 4; ++r) {
            int n_row = q0 + qd * 4 + r;
            tmp[((size_t)b * NTOK + n_row) * DMODEL + h * DK +  0 + ln] = f2b(o0[r] * linv[r]);
            tmp[((size_t)b * NTOK + n_row) * DMODEL + h * DK + 16 + ln] = f2b(o1[r] * linv[r]);
        }
    }
}

// ---------------- Kernel 5: output projection + bias + residual (LDS-staged, fp32 out) ----------------
__global__ __launch_bounds__(256) void oproj(
    const u16* __restrict__ tmp, const u16* __restrict__ wb,
    const float* __restrict__ bo, const float* __restrict__ x,
    float* __restrict__ out) {
    int mt = blockIdx.x;
    int ot = blockIdx.y;
    int b = blockIdx.z;
    const u16* Wo = wb + 3 * 65536;

    __shared__ u16 As[64][40];
    __shared__ u16 Bs[64][40];
    int t = threadIdx.x;
    int w = t >> 6, l = t & 63;
    int lr = t >> 2;
    int lc = (t & 3) * 8;
    int qd = l >> 4, ln = l & 15;

    const u16* ab = tmp + ((size_t)b * NTOK + mt * 64) * DMODEL;
    f32x4 acc[4] = {};
    for (int kb = 0; kb < 8; ++kb) {
        *(uint4*)&As[lr][lc] = *(const uint4*)&ab[lr * DMODEL + kb * 32 + lc];
        *(uint4*)&Bs[lr][lc] = *(const uint4*)&Wo[(ot * 64 + lr) * DMODEL + kb * 32 + lc];
        __syncthreads();
        bf16x8 af = *(const bf16x8*)&As[w * 16 + ln][qd * 8];
#pragma unroll
        for (int ns = 0; ns < 4; ++ns) {
            bf16x8 bf = *(const bf16x8*)&Bs[ns * 16 + ln][qd * 8];
            acc[ns] = __builtin_amdgcn_mfma_f32_16x16x32_bf16(af, bf, acc[ns], 0, 0, 0);
        }
        __syncthreads();
    }
    const float* xb = x + (size_t)b * PER_B;
    float* ob = out + (size_t)b * PER_B;
#pragma unroll
    for (int ns = 0; ns < 4; ++ns) {
        int o = ot * 64 + ns * 16 + ln;
        float bias_f = bo[o];
#pragma unroll
        for (int r = 0; r < 4; ++r) {
            int n_row = mt * 64 + w * 16 + qd * 4 + r;
            size_t idx = (size_t)n_row * DMODEL + o;
            ob[idx] = acc[ns][r] + bias_f + xb[idx];
        }
    }
}

extern "C" void kernel_launch(void* const* d_in, const int* in_sizes, int n_in,
                              void* d_out, int out_size, void* d_ws, size_t ws_size,
                              hipStream_t stream) {
    const float* x  = (const float*)d_in[0];
    const float* Wq = (const float*)d_in[1];
    const float* bq = (const float*)d_in[2];
    const float* Wk = (const float*)d_in[3];
    const float* bk = (const float*)d_in[4];
    const float* Wv = (const float*)d_in[5];
    const float* bv = (const float*)d_in[6];
    const float* Wo = (const float*)d_in[7];
    const float* bo = (const float*)d_in[8];
    float* out = (float*)d_out;

    char* ws = (char*)d_ws;
    float* part = (float*)ws;                          // 1 KB
    u16* wb  = (u16*)(ws + 1024);                      // 512 KB
    u16* xn  = (u16*)(ws + 1024 + (512u << 10));       // 4 MB (reused as attn output tmp)
    u16* qws = (u16*)(ws + 1024 + (512u << 10) + (4u << 20));
    u16* kws = (u16*)(ws + 1024 + (512u << 10) + (8u << 20));
    u16* vws = (u16*)(ws + 1024 + (512u << 10) + (12u << 20));  // transposed [bh][dv][n]
    u16* tmp = xn;

    // allow 149.4 KB dynamic LDS for attn (idempotent; host-side, capture-safe)
    hipFuncSetAttribute(reinterpret_cast<const void*>(attn),
                        hipFuncAttributeMaxDynamicSharedMemorySize, ATTN_LDS_BYTES);

    hipLaunchKernelGGL(prep, dim3(320), dim3(256), 0, stream, Wq, Wk, Wv, Wo, wb, x, part);
    hipLaunchKernelGGL(normT, dim3(32, 8, 8), dim3(32, 8), 0, stream, x, part, xn);
    hipLaunchKernelGGL(qkv_gemm, dim3(16, 12, 8), dim3(256), 0, stream,
                       xn, wb, bq, bk, bv, qws, kws, vws);
    hipLaunchKernelGGL(attn, dim3(64, 4), dim3(256), ATTN_LDS_BYTES, stream,
                       qws, kws, vws, tmp);
    hipLaunchKernelGGL(oproj, dim3(16, 4, 8), dim3(256), 0, stream, tmp, wb, bo, x, out);
}

// Round 8
// 184.064 us; speedup vs baseline: 1.1844x; 1.1844x over previous
//
#include <hip/hip_runtime.h>
#include <stdint.h>

typedef unsigned short u16;
typedef unsigned int u32;
typedef __attribute__((ext_vector_type(8))) short bf16x8;
typedef __attribute__((ext_vector_type(4))) float f32x4;

#define NTOK 1024      // H*W
#define DMODEL 256
#define NHEAD 8
#define DK 32
#define NBATCH 8
#define PER_B (DMODEL * NTOK)   // 262144

// ---- attn LDS layout (u16 units), r7's zero-conflict strides ----
#define KS_STRIDE 34                    // key row: 17 dwords (odd)
#define VT_STRIDE 134                   // dv row (128-key chunk): 67 dwords (odd)
#define PS_STRIDE 134
#define KD_SZ (128 * KS_STRIDE)         // 4352 u16 per buffer
#define VD_SZ (32 * VT_STRIDE)          // 4288 u16 per buffer
#define PD_SZ (16 * PS_STRIDE)          // 2144 u16 per (wave,sub)
#define KD_OFF 0
#define VD_OFF (2 * KD_SZ)                          // 8704
#define PD_OFF (VD_OFF + 2 * VD_SZ)                 // 17280
#define ATTN_LDS_U16 (PD_OFF + 8 * PD_SZ)           // 34432 u16
#define ATTN_LDS_BYTES (ATTN_LDS_U16 * 2)           // 68864 B -> 2 blocks/CU

__device__ __forceinline__ float b2f(u16 h) {
    union { unsigned u; float f; } c; c.u = ((unsigned)h) << 16; return c.f;
}
__device__ __forceinline__ u16 f2b(float f) {
    unsigned u = __float_as_uint(f);
    unsigned r = u + 0x7fffu + ((u >> 16) & 1u);
    return (u16)(r >> 16);
}

// ---------------- Kernel 1: fused weight-convert + LN partial sums ----------------
__global__ void prep(const float* __restrict__ Wq, const float* __restrict__ Wk,
                     const float* __restrict__ Wv, const float* __restrict__ Wo,
                     u16* __restrict__ wb,
                     const float* __restrict__ x, float* __restrict__ part) {
    int bx = blockIdx.x;
    int t = threadIdx.x;
    if (bx < 256) {
        int m = bx >> 6;
        const float* W = (m == 0) ? Wq : (m == 1) ? Wk : (m == 2) ? Wv : Wo;
        int i = ((bx & 63) * 256 + t) * 4;
        float4 v = *(const float4*)&W[i];
        ushort4 o;
        o.x = f2b(v.x); o.y = f2b(v.y); o.z = f2b(v.z); o.w = f2b(v.w);
        *(ushort4*)&wb[m * 65536 + i] = o;
        return;
    }
    int blk = bx - 256;
    int b = blk >> 3, sl = blk & 7;
    int w = t >> 6, l = t & 63;
    const float* xb = x + (size_t)b * PER_B + sl * (PER_B / 8);
    float s = 0.f, ss = 0.f;
    for (int base = 0; base < PER_B / 8; base += 1024) {
        float4 v = *(const float4*)&xb[base + t * 4];
        s += v.x + v.y + v.z + v.w;
        ss += v.x * v.x + v.y * v.y + v.z * v.z + v.w * v.w;
    }
    for (int d = 1; d < 64; d <<= 1) {
        s += __shfl_xor(s, d, 64);
        ss += __shfl_xor(ss, d, 64);
    }
    __shared__ float red[2][4];
    if (l == 0) { red[0][w] = s; red[1][w] = ss; }
    __syncthreads();
    if (t == 0) {
        float S = red[0][0] + red[0][1] + red[0][2] + red[0][3];
        float SS = red[1][0] + red[1][1] + red[1][2] + red[1][3];
        part[(b * 8 + sl) * 2] = S;
        part[(b * 8 + sl) * 2 + 1] = SS;
    }
}

// ---------------- Kernel 2: normalize + transpose [c,n] -> [n,c], fp32 -> bf16 ----------------
__global__ void normT(const float* __restrict__ x, const float* __restrict__ part,
                      u16* __restrict__ xn) {
    int b = blockIdx.z;
    int n0 = blockIdx.x * 32;
    int c0 = blockIdx.y * 32;
    int tx = threadIdx.x, ty = threadIdx.y;   // (32, 8)
    __shared__ float s_mu, s_rs;
    __shared__ float tile[32][33];
    if (tx == 0 && ty == 0) {
        float S = 0.f, SS = 0.f;
        for (int i = 0; i < 8; ++i) { S += part[(b * 8 + i) * 2]; SS += part[(b * 8 + i) * 2 + 1]; }
        float mu = S / (float)PER_B;
        float var = SS / (float)PER_B - mu * mu;
        s_mu = mu;
        s_rs = rsqrtf(var + 1e-5f);
    }
    __syncthreads();
    float mu = s_mu, rs = s_rs;
    const float* xb = x + (size_t)b * PER_B;
#pragma unroll
    for (int i = 0; i < 4; ++i) {
        int c = c0 + ty + i * 8;
        tile[ty + i * 8][tx] = (xb[c * NTOK + n0 + tx] - mu) * rs;
    }
    __syncthreads();
    u16* xnb = xn + (size_t)b * PER_B;
#pragma unroll
    for (int i = 0; i < 4; ++i) {
        int n = n0 + ty + i * 8;
        xnb[n * DMODEL + c0 + tx] = f2b(tile[tx][ty + i * 8]);
    }
}

// ---------------- Kernel 3: fused QKV GEMM, 128x128 tile, BK=64 ----------------
// C[8192][768] = xn[8192][256] x wb[768][256]^T. grid (64 mt, 6 nt), block 256 = 4 waves.
// Wave (wr=w>>1, wc=w&1) computes 64x64: 4x4 accs -> each ds_read_b128 feeds 4 MFMAs.
// sel = o>>8 is wave-uniform (64-col wave tiles never cross a 256 boundary).
__global__ __launch_bounds__(256, 4) void qkv_gemm(
    const u16* __restrict__ xn, const u16* __restrict__ wb,
    const float* __restrict__ bq, const float* __restrict__ bk,
    const float* __restrict__ bv,
    u16* __restrict__ qo, u16* __restrict__ ko, u16* __restrict__ vo) {
    int mt = blockIdx.x;          // 128 rows of 8192 (never crosses batch: 8 tiles/batch)
    int nt = blockIdx.y;          // 128 of 768 outputs
    __shared__ u16 As[128][72];
    __shared__ u16 Bs[128][72];

    int t = threadIdx.x;
    int w = t >> 6, l = t & 63;
    int wr = w >> 1, wc = w & 1;
    int qd = l >> 4, ln = l & 15;

    const u16* Ab = xn + (size_t)mt * 128 * DMODEL;
    const u16* Bb = wb + (size_t)nt * 128 * DMODEL;

    f32x4 acc[4][4] = {};
    for (int kb = 0; kb < 4; ++kb) {
#pragma unroll
        for (int i = 0; i < 4; ++i) {
            int idx = i * 256 + t;                    // 0..1023 uint4s
            int r = idx >> 3, c = (idx & 7) * 8;      // 8 uint4 per 64-col row
            *(uint4*)&As[r][c] = *(const uint4*)&Ab[r * DMODEL + kb * 64 + c];
            *(uint4*)&Bs[r][c] = *(const uint4*)&Bb[r * DMODEL + kb * 64 + c];
        }
        __syncthreads();
#pragma unroll
        for (int k2 = 0; k2 < 2; ++k2) {
            bf16x8 af[4], bf[4];
#pragma unroll
            for (int mr = 0; mr < 4; ++mr)
                af[mr] = *(const bf16x8*)&As[wr * 64 + mr * 16 + ln][k2 * 32 + qd * 8];
#pragma unroll
            for (int nc = 0; nc < 4; ++nc)
                bf[nc] = *(const bf16x8*)&Bs[wc * 64 + nc * 16 + ln][k2 * 32 + qd * 8];
#pragma unroll
            for (int mr = 0; mr < 4; ++mr)
#pragma unroll
                for (int nc = 0; nc < 4; ++nc)
                    acc[mr][nc] = __builtin_amdgcn_mfma_f32_16x16x32_bf16(af[mr], bf[nc], acc[mr][nc], 0, 0, 0);
        }
        __syncthreads();
    }

    int obase = nt * 128 + wc * 64;       // multiple of 64
    int sel = obase >> 8;                 // 0=q 1=k 2=v (wave-uniform)
    const float* bias = (sel == 0) ? bq : (sel == 1) ? bk : bv;
    float scale = (sel == 0) ? 0.25505654344884634f : 1.0f;   // DK^-0.5 * log2(e)
    int b = mt >> 3;
    int nbase = (mt & 7) * 128 + wr * 64;
#pragma unroll
    for (int nc = 0; nc < 4; ++nc) {
        int o = obase + nc * 16 + ln;     // global output col 0..767
        int oo = o & 255;
        float bias_f = bias[oo];
        int head = oo >> 5, d = oo & 31;
        if (sel < 2) {
            u16* outp = (sel == 0) ? qo : ko;
#pragma unroll
            for (int mr = 0; mr < 4; ++mr)
#pragma unroll
                for (int r = 0; r < 4; ++r) {
                    int n = nbase + mr * 16 + qd * 4 + r;
                    float v = (acc[mr][nc][r] + bias_f) * scale;
                    outp[(((size_t)b * NHEAD + head) * NTOK + n) * DK + d] = f2b(v);
                }
        } else {
#pragma unroll
            for (int mr = 0; mr < 4; ++mr) {
                int n0 = nbase + mr * 16 + qd * 4;
                ushort4 pk;
                pk.x = f2b(acc[mr][nc][0] + bias_f);
                pk.y = f2b(acc[mr][nc][1] + bias_f);
                pk.z = f2b(acc[mr][nc][2] + bias_f);
                pk.w = f2b(acc[mr][nc][3] + bias_f);
                *(ushort4*)&vo[(((size_t)b * NHEAD + head) * DK + d) * NTOK + n0] = pk;
            }
        }
    }
}

// ---------------- Kernel 4: attention — chunked LDS, dbuf, 2 q-subtiles/wave ----------------
// grid (64 bh, 8 qs) = 512 blocks = 2/CU (all co-resident); bh fastest -> XCD affinity.
// Block: 128 q x 1024 keys. Wave: 32 q (2 subtiles) -> every kf/vf LDS read feeds 2 MFMAs;
// two independent S/exp/P chains per wave. K/V chunks of 128 keys double-buffered in LDS,
// reg-prefetch a full chunk ahead, ONE barrier per chunk. P strides = r7's zero-conflict.
__global__ __launch_bounds__(256, 2) void attn(
    const u16* __restrict__ qws, const u16* __restrict__ kws,
    const u16* __restrict__ vtws, u16* __restrict__ tmp) {
    extern __shared__ u16 lds[];
    int bh = blockIdx.x;
    int qs = blockIdx.y;
    int b = bh >> 3, h = bh & 7;
    const u16* Q  = qws  + (size_t)bh * NTOK * DK;
    const u16* K  = kws  + (size_t)bh * NTOK * DK;
    const u16* Vt = vtws + (size_t)bh * DK * NTOK;   // [dv][n]

    int t = threadIdx.x;
    int w = t >> 6, l = t & 63;
    int qd = l >> 4, ln = l & 15;

    // Q fragments for the wave's two subtiles
    int qbase = qs * 128 + w * 32;
    bf16x8 qf0 = *(const bf16x8*)&Q[(qbase +  0 + ln) * DK + qd * 8];
    bf16x8 qf1 = *(const bf16x8*)&Q[(qbase + 16 + ln) * DK + qd * 8];

    // staging indices: 2 uint4/thread for K (8KB) and V (8KB) per chunk
    int krow0 = t >> 2,        kc0 = (t & 3) * 8;
    int krow1 = (t + 256) >> 2, kc1 = kc0;
    int vrow0 = t >> 4,        vc0 = (t & 15) * 8;
    int vrow1 = (t + 256) >> 4, vc1 = vc0;

    u16* P0 = lds + PD_OFF + (w * 2 + 0) * PD_SZ;
    u16* P1 = lds + PD_OFF + (w * 2 + 1) * PD_SZ;
    int wadr[8];
#pragma unroll
    for (int ns = 0; ns < 8; ++ns)
        wadr[ns] = ln * PS_STRIDE + ns * 16 + qd * 4;  // b64: keys ns*16+qd*4..+3, q-row ln
    int radr[4];
#pragma unroll
    for (int ks = 0; ks < 4; ++ks)
        radr[ks] = ln * PS_STRIDE + ks * 32 + qd * 8;

    float ls0 = 0.f, ls1 = 0.f;
    f32x4 oa[4] = {};   // [sub*2 + dvhalf]

    // prologue: chunk 0
    uint4 ka0 = *(const uint4*)&K[krow0 * DK + kc0];
    uint4 ka1 = *(const uint4*)&K[krow1 * DK + kc1];
    uint4 va0 = *(const uint4*)&Vt[vrow0 * NTOK + vc0];
    uint4 va1 = *(const uint4*)&Vt[vrow1 * NTOK + vc1];
    *(uint4*)&lds[KD_OFF + krow0 * KS_STRIDE + kc0] = ka0;
    *(uint4*)&lds[KD_OFF + krow1 * KS_STRIDE + kc1] = ka1;
    *(uint4*)&lds[VD_OFF + vrow0 * VT_STRIDE + vc0] = va0;
    *(uint4*)&lds[VD_OFF + vrow1 * VT_STRIDE + vc1] = va1;
    __syncthreads();

    for (int c = 0; c < 8; ++c) {
        int buf = c & 1;
        const u16* Kd = lds + KD_OFF + buf * KD_SZ;
        const u16* Vd = lds + VD_OFF + buf * VD_SZ;
        if (c < 7) {
            int k0 = (c + 1) * 128;
            ka0 = *(const uint4*)&K[(k0 + krow0) * DK + kc0];
            ka1 = *(const uint4*)&K[(k0 + krow1) * DK + kc1];
            va0 = *(const uint4*)&Vt[vrow0 * NTOK + k0 + vc0];
            va1 = *(const uint4*)&Vt[vrow1 * NTOK + k0 + vc1];
        }

        // ---- S phase: 8 key-tiles, both subtiles share each kf read ----
#pragma unroll
        for (int ns = 0; ns < 8; ++ns) {
            bf16x8 kf = *(const bf16x8*)&Kd[(ns * 16 + ln) * KS_STRIDE + qd * 8];
            f32x4 z = {0.f, 0.f, 0.f, 0.f};
            f32x4 s0 = __builtin_amdgcn_mfma_f32_16x16x32_bf16(kf, qf0, z, 0, 0, 0);
            f32x4 s1 = __builtin_amdgcn_mfma_f32_16x16x32_bf16(kf, qf1, z, 0, 0, 0);
            float a0 = __builtin_amdgcn_exp2f(s0[0]);
            float a1 = __builtin_amdgcn_exp2f(s0[1]);
            float a2 = __builtin_amdgcn_exp2f(s0[2]);
            float a3 = __builtin_amdgcn_exp2f(s0[3]);
            ls0 += (a0 + a1) + (a2 + a3);
            u32 d0 = __builtin_amdgcn_perm(__float_as_uint(a1), __float_as_uint(a0), 0x07060302u);
            u32 d1 = __builtin_amdgcn_perm(__float_as_uint(a3), __float_as_uint(a2), 0x07060302u);
            *(uint2*)&P0[wadr[ns]] = make_uint2(d0, d1);
            float b0 = __builtin_amdgcn_exp2f(s1[0]);
            float b1 = __builtin_amdgcn_exp2f(s1[1]);
            float b2 = __builtin_amdgcn_exp2f(s1[2]);
            float b3 = __builtin_amdgcn_exp2f(s1[3]);
            ls1 += (b0 + b1) + (b2 + b3);
            u32 e0 = __builtin_amdgcn_perm(__float_as_uint(b1), __float_as_uint(b0), 0x07060302u);
            u32 e1 = __builtin_amdgcn_perm(__float_as_uint(b3), __float_as_uint(b2), 0x07060302u);
            *(uint2*)&P1[wadr[ns]] = make_uint2(e0, e1);
        }

        // stage next chunk into the other buffer (in-order DS: queued after P writes)
        if (c < 7) {
            int nb = buf ^ 1;
            *(uint4*)&lds[KD_OFF + nb * KD_SZ + krow0 * KS_STRIDE + kc0] = ka0;
            *(uint4*)&lds[KD_OFF + nb * KD_SZ + krow1 * KS_STRIDE + kc1] = ka1;
            *(uint4*)&lds[VD_OFF + nb * VD_SZ + vrow0 * VT_STRIDE + vc0] = va0;
            *(uint4*)&lds[VD_OFF + nb * VD_SZ + vrow1 * VT_STRIDE + vc1] = va1;
        }

        // ---- PV phase: vf reads shared by both subtiles ----
#pragma unroll
        for (int ks = 0; ks < 4; ++ks) {
            bf16x8 vf0 = *(const bf16x8*)&Vd[( 0 + ln) * VT_STRIDE + ks * 32 + qd * 8];
            bf16x8 vf1 = *(const bf16x8*)&Vd[(16 + ln) * VT_STRIDE + ks * 32 + qd * 8];
            bf16x8 pf0 = *(const bf16x8*)&P0[radr[ks]];
            bf16x8 pf1 = *(const bf16x8*)&P1[radr[ks]];
            oa[0] = __builtin_amdgcn_mfma_f32_16x16x32_bf16(pf0, vf0, oa[0], 0, 0, 0);
            oa[1] = __builtin_amdgcn_mfma_f32_16x16x32_bf16(pf0, vf1, oa[1], 0, 0, 0);
            oa[2] = __builtin_amdgcn_mfma_f32_16x16x32_bf16(pf1, vf0, oa[2], 0, 0, 0);
            oa[3] = __builtin_amdgcn_mfma_f32_16x16x32_bf16(pf1, vf1, oa[3], 0, 0, 0);
        }
        if (c < 7) __syncthreads();
    }

    // l reductions (keys spread over qd groups)
    ls0 += __shfl_xor(ls0, 16, 64);
    ls0 += __shfl_xor(ls0, 32, 64);
    ls1 += __shfl_xor(ls1, 16, 64);
    ls1 += __shfl_xor(ls1, 32, 64);

    // epilogue per subtile: O rows q = qd*4 + r (C layout), cols dv = half*16 + ln
#pragma unroll
    for (int r = 0; r < 4; ++r) {
        float li0 = 1.0f / __shfl(ls0, qd * 4 + r, 64);
        float li1 = 1.0f / __shfl(ls1, qd * 4 + r, 64);
        int n0 = qbase + 0 + qd * 4 + r;
        int n1 = qbase + 16 + qd * 4 + r;
        size_t base0 = ((size_t)b * NTOK + n0) * DMODEL + h * DK;
        size_t base1 = ((size_t)b * NTOK + n1) * DMODEL + h * DK;
        tmp[base0 +  0 + ln] = f2b(oa[0][r] * li0);
        tmp[base0 + 16 + ln] = f2b(oa[1][r] * li0);
        tmp[base1 +  0 + ln] = f2b(oa[2][r] * li1);
        tmp[base1 + 16 + ln] = f2b(oa[3][r] * li1);
    }
}

// ---------------- Kernel 5: output projection + bias + residual (LDS-staged, fp32 out) ----------------
__global__ __launch_bounds__(256) void oproj(
    const u16* __restrict__ tmp, const u16* __restrict__ wb,
    const float* __restrict__ bo, const float* __restrict__ x,
    float* __restrict__ out) {
    int mt = blockIdx.x;
    int ot = blockIdx.y;
    int b = blockIdx.z;
    const u16* Wo = wb + 3 * 65536;

    __shared__ u16 As[64][40];
    __shared__ u16 Bs[64][40];
    int t = threadIdx.x;
    int w = t >> 6, l = t & 63;
    int lr = t >> 2;
    int lc = (t & 3) * 8;
    int qd = l >> 4, ln = l & 15;

    const u16* ab = tmp + ((size_t)b * NTOK + mt * 64) * DMODEL;
    f32x4 acc[4] = {};
    for (int kb = 0; kb < 8; ++kb) {
        *(uint4*)&As[lr][lc] = *(const uint4*)&ab[lr * DMODEL + kb * 32 + lc];
        *(uint4*)&Bs[lr][lc] = *(const uint4*)&Wo[(ot * 64 + lr) * DMODEL + kb * 32 + lc];
        __syncthreads();
        bf16x8 af = *(const bf16x8*)&As[w * 16 + ln][qd * 8];
#pragma unroll
        for (int ns = 0; ns < 4; ++ns) {
            bf16x8 bf = *(const bf16x8*)&Bs[ns * 16 + ln][qd * 8];
            acc[ns] = __builtin_amdgcn_mfma_f32_16x16x32_bf16(af, bf, acc[ns], 0, 0, 0);
        }
        __syncthreads();
    }
    const float* xb = x + (size_t)b * PER_B;
    float* ob = out + (size_t)b * PER_B;
#pragma unroll
    for (int ns = 0; ns < 4; ++ns) {
        int o = ot * 64 + ns * 16 + ln;
        float bias_f = bo[o];
#pragma unroll
        for (int r = 0; r < 4; ++r) {
            int n_row = mt * 64 + w * 16 + qd * 4 + r;
            size_t idx = (size_t)n_row * DMODEL + o;
            ob[idx] = acc[ns][r] + bias_f + xb[idx];
        }
    }
}

extern "C" void kernel_launch(void* const* d_in, const int* in_sizes, int n_in,
                              void* d_out, int out_size, void* d_ws, size_t ws_size,
                              hipStream_t stream) {
    const float* x  = (const float*)d_in[0];
    const float* Wq = (const float*)d_in[1];
    const float* bq = (const float*)d_in[2];
    const float* Wk = (const float*)d_in[3];
    const float* bk = (const float*)d_in[4];
    const float* Wv = (const float*)d_in[5];
    const float* bv = (const float*)d_in[6];
    const float* Wo = (const float*)d_in[7];
    const float* bo = (const float*)d_in[8];
    float* out = (float*)d_out;

    char* ws = (char*)d_ws;
    float* part = (float*)ws;                          // 1 KB
    u16* wb  = (u16*)(ws + 1024);                      // 512 KB
    u16* xn  = (u16*)(ws + 1024 + (512u << 10));       // 4 MB (reused as attn output tmp)
    u16* qws = (u16*)(ws + 1024 + (512u << 10) + (4u << 20));
    u16* kws = (u16*)(ws + 1024 + (512u << 10) + (8u << 20));
    u16* vws = (u16*)(ws + 1024 + (512u << 10) + (12u << 20));  // transposed [bh][dv][n]
    u16* tmp = xn;

    hipFuncSetAttribute(reinterpret_cast<const void*>(attn),
                        hipFuncAttributeMaxDynamicSharedMemorySize, ATTN_LDS_BYTES);

    hipLaunchKernelGGL(prep, dim3(320), dim3(256), 0, stream, Wq, Wk, Wv, Wo, wb, x, part);
    hipLaunchKernelGGL(normT, dim3(32, 8, 8), dim3(32, 8), 0, stream, x, part, xn);
    hipLaunchKernelGGL(qkv_gemm, dim3(64, 6), dim3(256), 0, stream,
                       xn, wb, bq, bk, bv, qws, kws, vws);
    hipLaunchKernelGGL(attn, dim3(64, 8), dim3(256), ATTN_LDS_BYTES, stream,
                       qws, kws, vws, tmp);
    hipLaunchKernelGGL(oproj, dim3(16, 4, 8), dim3(256), 0, stream, tmp, wb, bo, x, out);
}

// Round 9
// 162.434 us; speedup vs baseline: 1.3421x; 1.1332x over previous
//
#include <hip/hip_runtime.h>
#include <stdint.h>

typedef unsigned short u16;
typedef unsigned int u32;
typedef __attribute__((ext_vector_type(8))) short bf16x8;
typedef __attribute__((ext_vector_type(4))) float f32x4;

#define NTOK 1024      // H*W
#define DMODEL 256
#define NHEAD 8
#define DK 32
#define NBATCH 8
#define PER_B (DMODEL * NTOK)   // 262144

__device__ __forceinline__ float b2f(u16 h) {
    union { unsigned u; float f; } c; c.u = ((unsigned)h) << 16; return c.f;
}
__device__ __forceinline__ u16 f2b(float f) {
    unsigned u = __float_as_uint(f);
    unsigned r = u + 0x7fffu + ((u >> 16) & 1u);
    return (u16)(r >> 16);
}

// ---------------- Kernel 1: fused weight-convert + LN partial sums ----------------
__global__ void prep(const float* __restrict__ Wq, const float* __restrict__ Wk,
                     const float* __restrict__ Wv, const float* __restrict__ Wo,
                     u16* __restrict__ wb,
                     const float* __restrict__ x, float* __restrict__ part) {
    int bx = blockIdx.x;
    int t = threadIdx.x;
    if (bx < 256) {
        int m = bx >> 6;
        const float* W = (m == 0) ? Wq : (m == 1) ? Wk : (m == 2) ? Wv : Wo;
        int i = ((bx & 63) * 256 + t) * 4;
        float4 v = *(const float4*)&W[i];
        ushort4 o;
        o.x = f2b(v.x); o.y = f2b(v.y); o.z = f2b(v.z); o.w = f2b(v.w);
        *(ushort4*)&wb[m * 65536 + i] = o;
        return;
    }
    int blk = bx - 256;
    int b = blk >> 3, sl = blk & 7;
    int w = t >> 6, l = t & 63;
    const float* xb = x + (size_t)b * PER_B + sl * (PER_B / 8);
    float s = 0.f, ss = 0.f;
    for (int base = 0; base < PER_B / 8; base += 1024) {
        float4 v = *(const float4*)&xb[base + t * 4];
        s += v.x + v.y + v.z + v.w;
        ss += v.x * v.x + v.y * v.y + v.z * v.z + v.w * v.w;
    }
    for (int d = 1; d < 64; d <<= 1) {
        s += __shfl_xor(s, d, 64);
        ss += __shfl_xor(ss, d, 64);
    }
    __shared__ float red[2][4];
    if (l == 0) { red[0][w] = s; red[1][w] = ss; }
    __syncthreads();
    if (t == 0) {
        float S = red[0][0] + red[0][1] + red[0][2] + red[0][3];
        float SS = red[1][0] + red[1][1] + red[1][2] + red[1][3];
        part[(b * 8 + sl) * 2] = S;
        part[(b * 8 + sl) * 2 + 1] = SS;
    }
}

// ---------------- Kernel 2: normalize + transpose [c,n] -> [n,c], fp32 -> bf16 ----------------
__global__ void normT(const float* __restrict__ x, const float* __restrict__ part,
                      u16* __restrict__ xn) {
    int b = blockIdx.z;
    int n0 = blockIdx.x * 32;
    int c0 = blockIdx.y * 32;
    int tx = threadIdx.x, ty = threadIdx.y;   // (32, 8)
    __shared__ float s_mu, s_rs;
    __shared__ float tile[32][33];
    if (tx == 0 && ty == 0) {
        float S = 0.f, SS = 0.f;
        for (int i = 0; i < 8; ++i) { S += part[(b * 8 + i) * 2]; SS += part[(b * 8 + i) * 2 + 1]; }
        float mu = S / (float)PER_B;
        float var = SS / (float)PER_B - mu * mu;
        s_mu = mu;
        s_rs = rsqrtf(var + 1e-5f);
    }
    __syncthreads();
    float mu = s_mu, rs = s_rs;
    const float* xb = x + (size_t)b * PER_B;
#pragma unroll
    for (int i = 0; i < 4; ++i) {
        int c = c0 + ty + i * 8;
        tile[ty + i * 8][tx] = (xb[c * NTOK + n0 + tx] - mu) * rs;
    }
    __syncthreads();
    u16* xnb = xn + (size_t)b * PER_B;
#pragma unroll
    for (int i = 0; i < 4; ++i) {
        int n = n0 + ty + i * 8;
        xnb[n * DMODEL + c0 + tx] = f2b(tile[tx][ty + i * 8]);
    }
}

// ---------------- Kernel 3: fused QKV GEMM, 128x128 tile, BK=64 ----------------
__global__ __launch_bounds__(256, 4) void qkv_gemm(
    const u16* __restrict__ xn, const u16* __restrict__ wb,
    const float* __restrict__ bq, const float* __restrict__ bk,
    const float* __restrict__ bv,
    u16* __restrict__ qo, u16* __restrict__ ko, u16* __restrict__ vo) {
    int mt = blockIdx.x;
    int nt = blockIdx.y;
    __shared__ u16 As[128][72];
    __shared__ u16 Bs[128][72];

    int t = threadIdx.x;
    int w = t >> 6, l = t & 63;
    int wr = w >> 1, wc = w & 1;
    int qd = l >> 4, ln = l & 15;

    const u16* Ab = xn + (size_t)mt * 128 * DMODEL;
    const u16* Bb = wb + (size_t)nt * 128 * DMODEL;

    f32x4 acc[4][4] = {};
    for (int kb = 0; kb < 4; ++kb) {
#pragma unroll
        for (int i = 0; i < 4; ++i) {
            int idx = i * 256 + t;
            int r = idx >> 3, c = (idx & 7) * 8;
            *(uint4*)&As[r][c] = *(const uint4*)&Ab[r * DMODEL + kb * 64 + c];
            *(uint4*)&Bs[r][c] = *(const uint4*)&Bb[r * DMODEL + kb * 64 + c];
        }
        __syncthreads();
#pragma unroll
        for (int k2 = 0; k2 < 2; ++k2) {
            bf16x8 af[4], bf[4];
#pragma unroll
            for (int mr = 0; mr < 4; ++mr)
                af[mr] = *(const bf16x8*)&As[wr * 64 + mr * 16 + ln][k2 * 32 + qd * 8];
#pragma unroll
            for (int nc = 0; nc < 4; ++nc)
                bf[nc] = *(const bf16x8*)&Bs[wc * 64 + nc * 16 + ln][k2 * 32 + qd * 8];
#pragma unroll
            for (int mr = 0; mr < 4; ++mr)
#pragma unroll
                for (int nc = 0; nc < 4; ++nc)
                    acc[mr][nc] = __builtin_amdgcn_mfma_f32_16x16x32_bf16(af[mr], bf[nc], acc[mr][nc], 0, 0, 0);
        }
        __syncthreads();
    }

    int obase = nt * 128 + wc * 64;
    int sel = obase >> 8;
    const float* bias = (sel == 0) ? bq : (sel == 1) ? bk : bv;
    float scale = (sel == 0) ? 0.25505654344884634f : 1.0f;   // DK^-0.5 * log2(e)
    int b = mt >> 3;
    int nbase = (mt & 7) * 128 + wr * 64;
#pragma unroll
    for (int nc = 0; nc < 4; ++nc) {
        int o = obase + nc * 16 + ln;
        int oo = o & 255;
        float bias_f = bias[oo];
        int head = oo >> 5, d = oo & 31;
        if (sel < 2) {
            u16* outp = (sel == 0) ? qo : ko;
#pragma unroll
            for (int mr = 0; mr < 4; ++mr)
#pragma unroll
                for (int r = 0; r < 4; ++r) {
                    int n = nbase + mr * 16 + qd * 4 + r;
                    float v = (acc[mr][nc][r] + bias_f) * scale;
                    outp[(((size_t)b * NHEAD + head) * NTOK + n) * DK + d] = f2b(v);
                }
        } else {
#pragma unroll
            for (int mr = 0; mr < 4; ++mr) {
                int n0 = nbase + mr * 16 + qd * 4;
                ushort4 pk;
                pk.x = f2b(acc[mr][nc][0] + bias_f);
                pk.y = f2b(acc[mr][nc][1] + bias_f);
                pk.z = f2b(acc[mr][nc][2] + bias_f);
                pk.w = f2b(acc[mr][nc][3] + bias_f);
                *(ushort4*)&vo[(((size_t)b * NHEAD + head) * DK + d) * NTOK + n0] = pk;
            }
        }
    }
}

// ---------------- Kernel 4: attention — r5 base + 2 q-subtiles/wave + full residency ----------------
// grid (64 bh, 16 qb) = 1024 blocks x 4 waves = 4096 waves = exactly 4/SIMD (all resident).
// Wave = (qg = w>>1 -> 32 q, kh = w&1 -> 512 keys, 8 kt of 64). Global-direct K/V fragment
// loads (no barriers in loop), explicit next-kt prefetch (128-VGPR budget), each load feeds
// 2 MFMAs (subtiles share kf/vf). S^T = mfma(kf,qf) -> exp2 -> packed-b64 P (stride 66,
// <=2-way banks) -> PV. khalf merge through LDS (no-max softmax: pure adds).
__global__ __launch_bounds__(256, 4) void attn(
    const u16* __restrict__ qws, const u16* __restrict__ kws,
    const u16* __restrict__ vtws, u16* __restrict__ tmp) {
    int bh = blockIdx.x;
    int qb = blockIdx.y;
    int b = bh >> 3, h = bh & 7;
    const u16* Q  = qws  + (size_t)bh * NTOK * DK;
    const u16* K  = kws  + (size_t)bh * NTOK * DK;
    const u16* Vt = vtws + (size_t)bh * DK * NTOK;   // [dv][n]

    __shared__ u16 Ps[8][16 * 66];      // [wave*2+sub][q=16][key=64+pad]
    __shared__ float xch[2][64][19];    // khalf merge: 16 o + 2 l (+pad)

    int t = threadIdx.x;
    int w = t >> 6, l = t & 63;
    int qg = w >> 1, kh = w & 1;
    int qd = l >> 4, ln = l & 15;
    int kbase = kh * 512;
    int qbase = qb * 64 + qg * 32;

    bf16x8 qf0 = *(const bf16x8*)&Q[(qbase +  0 + ln) * DK + qd * 8];
    bf16x8 qf1 = *(const bf16x8*)&Q[(qbase + 16 + ln) * DK + qd * 8];

    u16* P0 = &Ps[w * 2 + 0][0];
    u16* P1 = &Ps[w * 2 + 1][0];
    int wadr[4];
#pragma unroll
    for (int ns = 0; ns < 4; ++ns)
        wadr[ns] = ln * 66 + ns * 16 + qd * 4;     // b64: keys ns*16+qd*4..+3, q-row ln
    int radr[2];
#pragma unroll
    for (int ks = 0; ks < 2; ++ks)
        radr[ks] = ln * 66 + ks * 32 + qd * 8;     // b128: keys ks*32+qd*8..+7, q-row ln

    float ls0 = 0.f, ls1 = 0.f;
    f32x4 oa[4] = {};   // [sub*2 + dvh]

    bf16x8 kf[4], vf[4];
#pragma unroll
    for (int ns = 0; ns < 4; ++ns)
        kf[ns] = *(const bf16x8*)&K[(kbase + ns * 16 + ln) * DK + qd * 8];
#pragma unroll
    for (int dvh = 0; dvh < 2; ++dvh)
#pragma unroll
        for (int ks = 0; ks < 2; ++ks)
            vf[dvh * 2 + ks] = *(const bf16x8*)&Vt[(dvh * 16 + ln) * NTOK + kbase + ks * 32 + qd * 8];

#pragma unroll
    for (int kt = 0; kt < 8; ++kt) {
        bf16x8 nkf[4], nvf[4];
        if (kt < 7) {
            int k1 = kbase + (kt + 1) * 64;
#pragma unroll
            for (int ns = 0; ns < 4; ++ns)
                nkf[ns] = *(const bf16x8*)&K[(k1 + ns * 16 + ln) * DK + qd * 8];
#pragma unroll
            for (int dvh = 0; dvh < 2; ++dvh)
#pragma unroll
                for (int ks = 0; ks < 2; ++ks)
                    nvf[dvh * 2 + ks] = *(const bf16x8*)&Vt[(dvh * 16 + ln) * NTOK + k1 + ks * 32 + qd * 8];
        }

        // S^T phase: kf shared by both subtiles; two independent exp/pack chains
#pragma unroll
        for (int ns = 0; ns < 4; ++ns) {
            f32x4 z = {0.f, 0.f, 0.f, 0.f};
            f32x4 s0 = __builtin_amdgcn_mfma_f32_16x16x32_bf16(kf[ns], qf0, z, 0, 0, 0);
            f32x4 s1 = __builtin_amdgcn_mfma_f32_16x16x32_bf16(kf[ns], qf1, z, 0, 0, 0);
            float a0 = __builtin_amdgcn_exp2f(s0[0]);
            float a1 = __builtin_amdgcn_exp2f(s0[1]);
            float a2 = __builtin_amdgcn_exp2f(s0[2]);
            float a3 = __builtin_amdgcn_exp2f(s0[3]);
            ls0 += (a0 + a1) + (a2 + a3);
            u32 d0 = __builtin_amdgcn_perm(__float_as_uint(a1), __float_as_uint(a0), 0x07060302u);
            u32 d1 = __builtin_amdgcn_perm(__float_as_uint(a3), __float_as_uint(a2), 0x07060302u);
            *(uint2*)&P0[wadr[ns]] = make_uint2(d0, d1);
            float b0 = __builtin_amdgcn_exp2f(s1[0]);
            float b1 = __builtin_amdgcn_exp2f(s1[1]);
            float b2 = __builtin_amdgcn_exp2f(s1[2]);
            float b3 = __builtin_amdgcn_exp2f(s1[3]);
            ls1 += (b0 + b1) + (b2 + b3);
            u32 e0 = __builtin_amdgcn_perm(__float_as_uint(b1), __float_as_uint(b0), 0x07060302u);
            u32 e1 = __builtin_amdgcn_perm(__float_as_uint(b3), __float_as_uint(b2), 0x07060302u);
            *(uint2*)&P1[wadr[ns]] = make_uint2(e0, e1);
        }

        // PV phase: vf shared by both subtiles
#pragma unroll
        for (int ks = 0; ks < 2; ++ks) {
            bf16x8 pf0 = *(const bf16x8*)&P0[radr[ks]];
            bf16x8 pf1 = *(const bf16x8*)&P1[radr[ks]];
            oa[0] = __builtin_amdgcn_mfma_f32_16x16x32_bf16(pf0, vf[0 + ks], oa[0], 0, 0, 0);
            oa[1] = __builtin_amdgcn_mfma_f32_16x16x32_bf16(pf0, vf[2 + ks], oa[1], 0, 0, 0);
            oa[2] = __builtin_amdgcn_mfma_f32_16x16x32_bf16(pf1, vf[0 + ks], oa[2], 0, 0, 0);
            oa[3] = __builtin_amdgcn_mfma_f32_16x16x32_bf16(pf1, vf[2 + ks], oa[3], 0, 0, 0);
        }

#pragma unroll
        for (int i = 0; i < 4; ++i) { kf[i] = nkf[i]; vf[i] = nvf[i]; }
    }

    // column sums: keys spread over qd groups -> reduce over qd
    ls0 += __shfl_xor(ls0, 16, 64);
    ls0 += __shfl_xor(ls0, 32, 64);
    ls1 += __shfl_xor(ls1, 16, 64);
    ls1 += __shfl_xor(ls1, 32, 64);

    // merge the two k-halves (pure adds)
    if (kh == 1) {
#pragma unroll
        for (int i = 0; i < 4; ++i)
#pragma unroll
            for (int j = 0; j < 4; ++j)
                xch[qg][l][i * 4 + j] = oa[i][j];
        xch[qg][l][16] = ls0;
        xch[qg][l][17] = ls1;
    }
    __syncthreads();
    if (kh == 0) {
#pragma unroll
        for (int i = 0; i < 4; ++i)
#pragma unroll
            for (int j = 0; j < 4; ++j)
                oa[i][j] += xch[qg][l][i * 4 + j];
        ls0 += xch[qg][l][16];
        ls1 += xch[qg][l][17];

#pragma unroll
        for (int r = 0; r < 4; ++r) {
            float li0 = 1.0f / __shfl(ls0, qd * 4 + r, 64);
            float li1 = 1.0f / __shfl(ls1, qd * 4 + r, 64);
            int n0 = qbase + 0 + qd * 4 + r;
            int n1 = qbase + 16 + qd * 4 + r;
            size_t base0 = ((size_t)b * NTOK + n0) * DMODEL + h * DK;
            size_t base1 = ((size_t)b * NTOK + n1) * DMODEL + h * DK;
            tmp[base0 +  0 + ln] = f2b(oa[0][r] * li0);
            tmp[base0 + 16 + ln] = f2b(oa[1][r] * li0);
            tmp[base1 +  0 + ln] = f2b(oa[2][r] * li1);
            tmp[base1 + 16 + ln] = f2b(oa[3][r] * li1);
        }
    }
}

// ---------------- Kernel 5: output projection + bias + residual (LDS-staged, fp32 out) ----------------
__global__ __launch_bounds__(256) void oproj(
    const u16* __restrict__ tmp, const u16* __restrict__ wb,
    const float* __restrict__ bo, const float* __restrict__ x,
    float* __restrict__ out) {
    int mt = blockIdx.x;
    int ot = blockIdx.y;
    int b = blockIdx.z;
    const u16* Wo = wb + 3 * 65536;

    __shared__ u16 As[64][40];
    __shared__ u16 Bs[64][40];
    int t = threadIdx.x;
    int w = t >> 6, l = t & 63;
    int lr = t >> 2;
    int lc = (t & 3) * 8;
    int qd = l >> 4, ln = l & 15;

    const u16* ab = tmp + ((size_t)b * NTOK + mt * 64) * DMODEL;
    f32x4 acc[4] = {};
    for (int kb = 0; kb < 8; ++kb) {
        *(uint4*)&As[lr][lc] = *(const uint4*)&ab[lr * DMODEL + kb * 32 + lc];
        *(uint4*)&Bs[lr][lc] = *(const uint4*)&Wo[(ot * 64 + lr) * DMODEL + kb * 32 + lc];
        __syncthreads();
        bf16x8 af = *(const bf16x8*)&As[w * 16 + ln][qd * 8];
#pragma unroll
        for (int ns = 0; ns < 4; ++ns) {
            bf16x8 bf = *(const bf16x8*)&Bs[ns * 16 + ln][qd * 8];
            acc[ns] = __builtin_amdgcn_mfma_f32_16x16x32_bf16(af, bf, acc[ns], 0, 0, 0);
        }
        __syncthreads();
    }
    const float* xb = x + (size_t)b * PER_B;
    float* ob = out + (size_t)b * PER_B;
#pragma unroll
    for (int ns = 0; ns < 4; ++ns) {
        int o = ot * 64 + ns * 16 + ln;
        float bias_f = bo[o];
#pragma unroll
        for (int r = 0; r < 4; ++r) {
            int n_row = mt * 64 + w * 16 + qd * 4 + r;
            size_t idx = (size_t)n_row * DMODEL + o;
            ob[idx] = acc[ns][r] + bias_f + xb[idx];
        }
    }
}

extern "C" void kernel_launch(void* const* d_in, const int* in_sizes, int n_in,
                              void* d_out, int out_size, void* d_ws, size_t ws_size,
                              hipStream_t stream) {
    const float* x  = (const float*)d_in[0];
    const float* Wq = (const float*)d_in[1];
    const float* bq = (const float*)d_in[2];
    const float* Wk = (const float*)d_in[3];
    const float* bk = (const float*)d_in[4];
    const float* Wv = (const float*)d_in[5];
    const float* bv = (const float*)d_in[6];
    const float* Wo = (const float*)d_in[7];
    const float* bo = (const float*)d_in[8];
    float* out = (float*)d_out;

    char* ws = (char*)d_ws;
    float* part = (float*)ws;                          // 1 KB
    u16* wb  = (u16*)(ws + 1024);                      // 512 KB
    u16* xn  = (u16*)(ws + 1024 + (512u << 10));       // 4 MB (reused as attn output tmp)
    u16* qws = (u16*)(ws + 1024 + (512u << 10) + (4u << 20));
    u16* kws = (u16*)(ws + 1024 + (512u << 10) + (8u << 20));
    u16* vws = (u16*)(ws + 1024 + (512u << 10) + (12u << 20));  // transposed [bh][dv][n]
    u16* tmp = xn;

    hipLaunchKernelGGL(prep, dim3(320), dim3(256), 0, stream, Wq, Wk, Wv, Wo, wb, x, part);
    hipLaunchKernelGGL(normT, dim3(32, 8, 8), dim3(32, 8), 0, stream, x, part, xn);
    hipLaunchKernelGGL(qkv_gemm, dim3(64, 6), dim3(256), 0, stream,
                       xn, wb, bq, bk, bv, qws, kws, vws);
    hipLaunchKernelGGL(attn, dim3(64, 16), dim3(256), 0, stream, qws, kws, vws, tmp);
    hipLaunchKernelGGL(oproj, dim3(16, 4, 8), dim3(256), 0, stream, tmp, wb, bo, x, out);
}

// Round 10
// 150.411 us; speedup vs baseline: 1.4494x; 1.0799x over previous
//
#include <hip/hip_runtime.h>
#include <stdint.h>

typedef unsigned short u16;
typedef unsigned int u32;
typedef __attribute__((ext_vector_type(8))) short bf16x8;
typedef __attribute__((ext_vector_type(4))) float f32x4;

#define NTOK 1024      // H*W
#define DMODEL 256
#define NHEAD 8
#define DK 32
#define NBATCH 8
#define PER_B (DMODEL * NTOK)   // 262144

__device__ __forceinline__ float b2f(u16 h) {
    union { unsigned u; float f; } c; c.u = ((unsigned)h) << 16; return c.f;
}
__device__ __forceinline__ u16 f2b(float f) {
    unsigned u = __float_as_uint(f);
    unsigned r = u + 0x7fffu + ((u >> 16) & 1u);
    return (u16)(r >> 16);
}

// ---------------- Kernel 1: fused weight-convert + LN partial sums ----------------
__global__ void prep(const float* __restrict__ Wq, const float* __restrict__ Wk,
                     const float* __restrict__ Wv, const float* __restrict__ Wo,
                     u16* __restrict__ wb,
                     const float* __restrict__ x, float* __restrict__ part) {
    int bx = blockIdx.x;
    int t = threadIdx.x;
    if (bx < 256) {
        int m = bx >> 6;
        const float* W = (m == 0) ? Wq : (m == 1) ? Wk : (m == 2) ? Wv : Wo;
        int i = ((bx & 63) * 256 + t) * 4;
        float4 v = *(const float4*)&W[i];
        ushort4 o;
        o.x = f2b(v.x); o.y = f2b(v.y); o.z = f2b(v.z); o.w = f2b(v.w);
        *(ushort4*)&wb[m * 65536 + i] = o;
        return;
    }
    int blk = bx - 256;
    int b = blk >> 3, sl = blk & 7;
    int w = t >> 6, l = t & 63;
    const float* xb = x + (size_t)b * PER_B + sl * (PER_B / 8);
    float s = 0.f, ss = 0.f;
    for (int base = 0; base < PER_B / 8; base += 1024) {
        float4 v = *(const float4*)&xb[base + t * 4];
        s += v.x + v.y + v.z + v.w;
        ss += v.x * v.x + v.y * v.y + v.z * v.z + v.w * v.w;
    }
    for (int d = 1; d < 64; d <<= 1) {
        s += __shfl_xor(s, d, 64);
        ss += __shfl_xor(ss, d, 64);
    }
    __shared__ float red[2][4];
    if (l == 0) { red[0][w] = s; red[1][w] = ss; }
    __syncthreads();
    if (t == 0) {
        float S = red[0][0] + red[0][1] + red[0][2] + red[0][3];
        float SS = red[1][0] + red[1][1] + red[1][2] + red[1][3];
        part[(b * 8 + sl) * 2] = S;
        part[(b * 8 + sl) * 2 + 1] = SS;
    }
}

// ---------------- Kernel 2: normalize + transpose [c,n] -> [n,c], fp32 -> bf16 ----------------
__global__ void normT(const float* __restrict__ x, const float* __restrict__ part,
                      u16* __restrict__ xn) {
    int b = blockIdx.z;
    int n0 = blockIdx.x * 32;
    int c0 = blockIdx.y * 32;
    int tx = threadIdx.x, ty = threadIdx.y;   // (32, 8)
    __shared__ float s_mu, s_rs;
    __shared__ float tile[32][33];
    if (tx == 0 && ty == 0) {
        float S = 0.f, SS = 0.f;
        for (int i = 0; i < 8; ++i) { S += part[(b * 8 + i) * 2]; SS += part[(b * 8 + i) * 2 + 1]; }
        float mu = S / (float)PER_B;
        float var = SS / (float)PER_B - mu * mu;
        s_mu = mu;
        s_rs = rsqrtf(var + 1e-5f);
    }
    __syncthreads();
    float mu = s_mu, rs = s_rs;
    const float* xb = x + (size_t)b * PER_B;
#pragma unroll
    for (int i = 0; i < 4; ++i) {
        int c = c0 + ty + i * 8;
        tile[ty + i * 8][tx] = (xb[c * NTOK + n0 + tx] - mu) * rs;
    }
    __syncthreads();
    u16* xnb = xn + (size_t)b * PER_B;
#pragma unroll
    for (int i = 0; i < 4; ++i) {
        int n = n0 + ty + i * 8;
        xnb[n * DMODEL + c0 + tx] = f2b(tile[tx][ty + i * 8]);
    }
}

// ---------------- Kernel 3: fused QKV GEMM, 128x128 tile, BK=64 ----------------
// launch_bounds(256,2): empirical VGPR cap ~128 (N=4 capped at 64 and spilled).
__global__ __launch_bounds__(256, 2) void qkv_gemm(
    const u16* __restrict__ xn, const u16* __restrict__ wb,
    const float* __restrict__ bq, const float* __restrict__ bk,
    const float* __restrict__ bv,
    u16* __restrict__ qo, u16* __restrict__ ko, u16* __restrict__ vo) {
    int mt = blockIdx.x;
    int nt = blockIdx.y;
    __shared__ u16 As[128][72];
    __shared__ u16 Bs[128][72];

    int t = threadIdx.x;
    int w = t >> 6, l = t & 63;
    int wr = w >> 1, wc = w & 1;
    int qd = l >> 4, ln = l & 15;

    const u16* Ab = xn + (size_t)mt * 128 * DMODEL;
    const u16* Bb = wb + (size_t)nt * 128 * DMODEL;

    f32x4 acc[4][4] = {};
    for (int kb = 0; kb < 4; ++kb) {
#pragma unroll
        for (int i = 0; i < 4; ++i) {
            int idx = i * 256 + t;
            int r = idx >> 3, c = (idx & 7) * 8;
            *(uint4*)&As[r][c] = *(const uint4*)&Ab[r * DMODEL + kb * 64 + c];
            *(uint4*)&Bs[r][c] = *(const uint4*)&Bb[r * DMODEL + kb * 64 + c];
        }
        __syncthreads();
#pragma unroll
        for (int k2 = 0; k2 < 2; ++k2) {
            bf16x8 af[4], bf[4];
#pragma unroll
            for (int mr = 0; mr < 4; ++mr)
                af[mr] = *(const bf16x8*)&As[wr * 64 + mr * 16 + ln][k2 * 32 + qd * 8];
#pragma unroll
            for (int nc = 0; nc < 4; ++nc)
                bf[nc] = *(const bf16x8*)&Bs[wc * 64 + nc * 16 + ln][k2 * 32 + qd * 8];
#pragma unroll
            for (int mr = 0; mr < 4; ++mr)
#pragma unroll
                for (int nc = 0; nc < 4; ++nc)
                    acc[mr][nc] = __builtin_amdgcn_mfma_f32_16x16x32_bf16(af[mr], bf[nc], acc[mr][nc], 0, 0, 0);
        }
        __syncthreads();
    }

    int obase = nt * 128 + wc * 64;
    int sel = obase >> 8;
    const float* bias = (sel == 0) ? bq : (sel == 1) ? bk : bv;
    float scale = (sel == 0) ? 0.25505654344884634f : 1.0f;   // DK^-0.5 * log2(e)
    int b = mt >> 3;
    int nbase = (mt & 7) * 128 + wr * 64;
#pragma unroll
    for (int nc = 0; nc < 4; ++nc) {
        int o = obase + nc * 16 + ln;
        int oo = o & 255;
        float bias_f = bias[oo];
        int head = oo >> 5, d = oo & 31;
        if (sel < 2) {
            u16* outp = (sel == 0) ? qo : ko;
#pragma unroll
            for (int mr = 0; mr < 4; ++mr)
#pragma unroll
                for (int r = 0; r < 4; ++r) {
                    int n = nbase + mr * 16 + qd * 4 + r;
                    float v = (acc[mr][nc][r] + bias_f) * scale;
                    outp[(((size_t)b * NHEAD + head) * NTOK + n) * DK + d] = f2b(v);
                }
        } else {
#pragma unroll
            for (int mr = 0; mr < 4; ++mr) {
                int n0 = nbase + mr * 16 + qd * 4;
                ushort4 pk;
                pk.x = f2b(acc[mr][nc][0] + bias_f);
                pk.y = f2b(acc[mr][nc][1] + bias_f);
                pk.z = f2b(acc[mr][nc][2] + bias_f);
                pk.w = f2b(acc[mr][nc][3] + bias_f);
                *(ushort4*)&vo[(((size_t)b * NHEAD + head) * DK + d) * NTOK + n0] = pk;
            }
        }
    }
}

// ---------------- Kernel 4: attention — r9 structure, REGISTER-FIXED ----------------
// launch_bounds(256,2): empirical VGPR cap ~128 (r9's (256,4) capped at 64 -> 128 MB of
// scratch spill traffic, the real r9 limiter). Live set ~102 VGPR now fits: explicit
// next-kt prefetch of all 8 K/V fragments stays in registers. grid (64 bh, 16 qb):
// 4096 waves; at 128 VGPR -> 4 waves/SIMD -> fully resident. Wave = (qg -> 32 q, kh -> 512 keys).
// Each kf/vf load feeds 2 MFMAs (subtiles); S^T=mfma(kf,qf) -> exp2 -> packed-b64 P
// (stride 66, <=2-way banks) -> PV. khalf merge via LDS (pure adds).
__global__ __launch_bounds__(256, 2) void attn(
    const u16* __restrict__ qws, const u16* __restrict__ kws,
    const u16* __restrict__ vtws, u16* __restrict__ tmp) {
    int bh = blockIdx.x;
    int qb = blockIdx.y;
    int b = bh >> 3, h = bh & 7;
    const u16* Q  = qws  + (size_t)bh * NTOK * DK;
    const u16* K  = kws  + (size_t)bh * NTOK * DK;
    const u16* Vt = vtws + (size_t)bh * DK * NTOK;   // [dv][n]

    __shared__ u16 Ps[8][16 * 66];      // [wave*2+sub][q=16][key=64+pad]
    __shared__ float xch[2][64][19];    // khalf merge: 16 o + 2 l (+pad)

    int t = threadIdx.x;
    int w = t >> 6, l = t & 63;
    int qg = w >> 1, kh = w & 1;
    int qd = l >> 4, ln = l & 15;
    int kbase = kh * 512;
    int qbase = qb * 64 + qg * 32;

    bf16x8 qf0 = *(const bf16x8*)&Q[(qbase +  0 + ln) * DK + qd * 8];
    bf16x8 qf1 = *(const bf16x8*)&Q[(qbase + 16 + ln) * DK + qd * 8];

    u16* P0 = &Ps[w * 2 + 0][0];
    u16* P1 = &Ps[w * 2 + 1][0];
    int wadr[4];
#pragma unroll
    for (int ns = 0; ns < 4; ++ns)
        wadr[ns] = ln * 66 + ns * 16 + qd * 4;     // b64: keys ns*16+qd*4..+3, q-row ln
    int radr[2];
#pragma unroll
    for (int ks = 0; ks < 2; ++ks)
        radr[ks] = ln * 66 + ks * 32 + qd * 8;     // b128: keys ks*32+qd*8..+7, q-row ln

    float ls0 = 0.f, ls1 = 0.f;
    f32x4 oa[4] = {};   // [sub*2 + dvh]

    bf16x8 kf[4], vf[4];
#pragma unroll
    for (int ns = 0; ns < 4; ++ns)
        kf[ns] = *(const bf16x8*)&K[(kbase + ns * 16 + ln) * DK + qd * 8];
#pragma unroll
    for (int dvh = 0; dvh < 2; ++dvh)
#pragma unroll
        for (int ks = 0; ks < 2; ++ks)
            vf[dvh * 2 + ks] = *(const bf16x8*)&Vt[(dvh * 16 + ln) * NTOK + kbase + ks * 32 + qd * 8];

#pragma unroll
    for (int kt = 0; kt < 8; ++kt) {
        bf16x8 nkf[4], nvf[4];
        if (kt < 7) {
            int k1 = kbase + (kt + 1) * 64;
#pragma unroll
            for (int ns = 0; ns < 4; ++ns)
                nkf[ns] = *(const bf16x8*)&K[(k1 + ns * 16 + ln) * DK + qd * 8];
#pragma unroll
            for (int dvh = 0; dvh < 2; ++dvh)
#pragma unroll
                for (int ks = 0; ks < 2; ++ks)
                    nvf[dvh * 2 + ks] = *(const bf16x8*)&Vt[(dvh * 16 + ln) * NTOK + k1 + ks * 32 + qd * 8];
        }

        // S^T phase: kf shared by both subtiles; two independent exp/pack chains
#pragma unroll
        for (int ns = 0; ns < 4; ++ns) {
            f32x4 z = {0.f, 0.f, 0.f, 0.f};
            f32x4 s0 = __builtin_amdgcn_mfma_f32_16x16x32_bf16(kf[ns], qf0, z, 0, 0, 0);
            f32x4 s1 = __builtin_amdgcn_mfma_f32_16x16x32_bf16(kf[ns], qf1, z, 0, 0, 0);
            float a0 = __builtin_amdgcn_exp2f(s0[0]);
            float a1 = __builtin_amdgcn_exp2f(s0[1]);
            float a2 = __builtin_amdgcn_exp2f(s0[2]);
            float a3 = __builtin_amdgcn_exp2f(s0[3]);
            ls0 += (a0 + a1) + (a2 + a3);
            u32 d0 = __builtin_amdgcn_perm(__float_as_uint(a1), __float_as_uint(a0), 0x07060302u);
            u32 d1 = __builtin_amdgcn_perm(__float_as_uint(a3), __float_as_uint(a2), 0x07060302u);
            *(uint2*)&P0[wadr[ns]] = make_uint2(d0, d1);
            float b0 = __builtin_amdgcn_exp2f(s1[0]);
            float b1 = __builtin_amdgcn_exp2f(s1[1]);
            float b2 = __builtin_amdgcn_exp2f(s1[2]);
            float b3 = __builtin_amdgcn_exp2f(s1[3]);
            ls1 += (b0 + b1) + (b2 + b3);
            u32 e0 = __builtin_amdgcn_perm(__float_as_uint(b1), __float_as_uint(b0), 0x07060302u);
            u32 e1 = __builtin_amdgcn_perm(__float_as_uint(b3), __float_as_uint(b2), 0x07060302u);
            *(uint2*)&P1[wadr[ns]] = make_uint2(e0, e1);
        }

        // PV phase: vf shared by both subtiles
#pragma unroll
        for (int ks = 0; ks < 2; ++ks) {
            bf16x8 pf0 = *(const bf16x8*)&P0[radr[ks]];
            bf16x8 pf1 = *(const bf16x8*)&P1[radr[ks]];
            oa[0] = __builtin_amdgcn_mfma_f32_16x16x32_bf16(pf0, vf[0 + ks], oa[0], 0, 0, 0);
            oa[1] = __builtin_amdgcn_mfma_f32_16x16x32_bf16(pf0, vf[2 + ks], oa[1], 0, 0, 0);
            oa[2] = __builtin_amdgcn_mfma_f32_16x16x32_bf16(pf1, vf[0 + ks], oa[2], 0, 0, 0);
            oa[3] = __builtin_amdgcn_mfma_f32_16x16x32_bf16(pf1, vf[2 + ks], oa[3], 0, 0, 0);
        }

#pragma unroll
        for (int i = 0; i < 4; ++i) { kf[i] = nkf[i]; vf[i] = nvf[i]; }
    }

    // column sums: keys spread over qd groups -> reduce over qd
    ls0 += __shfl_xor(ls0, 16, 64);
    ls0 += __shfl_xor(ls0, 32, 64);
    ls1 += __shfl_xor(ls1, 16, 64);
    ls1 += __shfl_xor(ls1, 32, 64);

    // merge the two k-halves (pure adds)
    if (kh == 1) {
#pragma unroll
        for (int i = 0; i < 4; ++i)
#pragma unroll
            for (int j = 0; j < 4; ++j)
                xch[qg][l][i * 4 + j] = oa[i][j];
        xch[qg][l][16] = ls0;
        xch[qg][l][17] = ls1;
    }
    __syncthreads();
    if (kh == 0) {
#pragma unroll
        for (int i = 0; i < 4; ++i)
#pragma unroll
            for (int j = 0; j < 4; ++j)
                oa[i][j] += xch[qg][l][i * 4 + j];
        ls0 += xch[qg][l][16];
        ls1 += xch[qg][l][17];

#pragma unroll
        for (int r = 0; r < 4; ++r) {
            float li0 = 1.0f / __shfl(ls0, qd * 4 + r, 64);
            float li1 = 1.0f / __shfl(ls1, qd * 4 + r, 64);
            int n0 = qbase + 0 + qd * 4 + r;
            int n1 = qbase + 16 + qd * 4 + r;
            size_t base0 = ((size_t)b * NTOK + n0) * DMODEL + h * DK;
            size_t base1 = ((size_t)b * NTOK + n1) * DMODEL + h * DK;
            tmp[base0 +  0 + ln] = f2b(oa[0][r] * li0);
            tmp[base0 + 16 + ln] = f2b(oa[1][r] * li0);
            tmp[base1 +  0 + ln] = f2b(oa[2][r] * li1);
            tmp[base1 + 16 + ln] = f2b(oa[3][r] * li1);
        }
    }
}

// ---------------- Kernel 5: output projection + bias + residual (LDS-staged, fp32 out) ----------------
__global__ __launch_bounds__(256) void oproj(
    const u16* __restrict__ tmp, const u16* __restrict__ wb,
    const float* __restrict__ bo, const float* __restrict__ x,
    float* __restrict__ out) {
    int mt = blockIdx.x;
    int ot = blockIdx.y;
    int b = blockIdx.z;
    const u16* Wo = wb + 3 * 65536;

    __shared__ u16 As[64][40];
    __shared__ u16 Bs[64][40];
    int t = threadIdx.x;
    int w = t >> 6, l = t & 63;
    int lr = t >> 2;
    int lc = (t & 3) * 8;
    int qd = l >> 4, ln = l & 15;

    const u16* ab = tmp + ((size_t)b * NTOK + mt * 64) * DMODEL;
    f32x4 acc[4] = {};
    for (int kb = 0; kb < 8; ++kb) {
        *(uint4*)&As[lr][lc] = *(const uint4*)&ab[lr * DMODEL + kb * 32 + lc];
        *(uint4*)&Bs[lr][lc] = *(const uint4*)&Wo[(ot * 64 + lr) * DMODEL + kb * 32 + lc];
        __syncthreads();
        bf16x8 af = *(const bf16x8*)&As[w * 16 + ln][qd * 8];
#pragma unroll
        for (int ns = 0; ns < 4; ++ns) {
            bf16x8 bf = *(const bf16x8*)&Bs[ns * 16 + ln][qd * 8];
            acc[ns] = __builtin_amdgcn_mfma_f32_16x16x32_bf16(af, bf, acc[ns], 0, 0, 0);
        }
        __syncthreads();
    }
    const float* xb = x + (size_t)b * PER_B;
    float* ob = out + (size_t)b * PER_B;
#pragma unroll
    for (int ns = 0; ns < 4; ++ns) {
        int o = ot * 64 + ns * 16 + ln;
        float bias_f = bo[o];
#pragma unroll
        for (int r = 0; r < 4; ++r) {
            int n_row = mt * 64 + w * 16 + qd * 4 + r;
            size_t idx = (size_t)n_row * DMODEL + o;
            ob[idx] = acc[ns][r] + bias_f + xb[idx];
        }
    }
}

extern "C" void kernel_launch(void* const* d_in, const int* in_sizes, int n_in,
                              void* d_out, int out_size, void* d_ws, size_t ws_size,
                              hipStream_t stream) {
    const float* x  = (const float*)d_in[0];
    const float* Wq = (const float*)d_in[1];
    const float* bq = (const float*)d_in[2];
    const float* Wk = (const float*)d_in[3];
    const float* bk = (const float*)d_in[4];
    const float* Wv = (const float*)d_in[5];
    const float* bv = (const float*)d_in[6];
    const float* Wo = (const float*)d_in[7];
    const float* bo = (const float*)d_in[8];
    float* out = (float*)d_out;

    char* ws = (char*)d_ws;
    float* part = (float*)ws;                          // 1 KB
    u16* wb  = (u16*)(ws + 1024);                      // 512 KB
    u16* xn  = (u16*)(ws + 1024 + (512u << 10));       // 4 MB (reused as attn output tmp)
    u16* qws = (u16*)(ws + 1024 + (512u << 10) + (4u << 20));
    u16* kws = (u16*)(ws + 1024 + (512u << 10) + (8u << 20));
    u16* vws = (u16*)(ws + 1024 + (512u << 10) + (12u << 20));  // transposed [bh][dv][n]
    u16* tmp = xn;

    hipLaunchKernelGGL(prep, dim3(320), dim3(256), 0, stream, Wq, Wk, Wv, Wo, wb, x, part);
    hipLaunchKernelGGL(normT, dim3(32, 8, 8), dim3(32, 8), 0, stream, x, part, xn);
    hipLaunchKernelGGL(qkv_gemm, dim3(64, 6), dim3(256), 0, stream,
                       xn, wb, bq, bk, bv, qws, kws, vws);
    hipLaunchKernelGGL(attn, dim3(64, 16), dim3(256), 0, stream, qws, kws, vws, tmp);
    hipLaunchKernelGGL(oproj, dim3(16, 4, 8), dim3(256), 0, stream, tmp, wb, bo, x, out);
}